// Round 3
// baseline (1303.394 us; speedup 1.0000x reference)
//
#include <hip/hip_runtime.h>
#include <math.h>
#include <stdint.h>

typedef __bf16 bf16;
typedef __bf16 bf16x8 __attribute__((ext_vector_type(8)));
typedef float f32x4 __attribute__((ext_vector_type(4)));

#define DEV __device__ __forceinline__

// async global->LDS, 16B per lane. LDS dest must be wave-uniform base + lane*16.
DEV void g2l16(void* lds, const void* g) {
    __builtin_amdgcn_global_load_lds(
        (const __attribute__((address_space(1))) uint32_t*)g,
        (__attribute__((address_space(3))) uint32_t*)lds,
        16, 0, 0);
}

// Fast gelu: x * sigmoid(1.5957691216*(x + 0.044715 x^3)).
DEV float gelu_fast(float x) {
    float u = -1.5957691216f * __builtin_fmaf(0.044715f * x, x * x, x);
    return x * __builtin_amdgcn_rcpf(1.f + __expf(u));
}

// ---------------------------------------------------------------------------
// Phase-split deep-pipelined GEMM: C = alpha * A @ Bt^T (+ epilogue).
// Tile 256x128, BK=64, 512 threads = 8 waves (4M x 2N, 64x64 each, acc[4][4]).
// 3-deep LDS ring (3 x (A 32KB + B 16KB) = 144KB). Two phases per K-tile,
// each phase: {stage 3 g2l16 of tile t+2 | 8 ds_read_b128 (k-step frags) |
// barrier | lgkmcnt(0) | 16 MFMA w/ setprio | barrier}. vmcnt(6) once per
// K-tile waits ONLY tile t+1's 6 loads; tile t+2's 6 stay in flight across
// the barrier (counted vmcnt, never drained). Raw s_barrier (no __syncthreads
// -> no vmcnt(0) drain). LDS k-chunked [kc][row][8]: conflict-free ds_read_b128.
// Race-freedom: per-wave reads of buf b retire (lgkmcnt(0) before MFMA)
// before b's closing barrier; b is re-staged only after that barrier; FIFO
// vmcnt makes the 6-count exact. Tail stages 2 garbage tiles (<=256B past
// operand ends; all land in allocated ws regions; never consumed).
// EPI: 0 plain*alpha; 1 bias+gelu; 2 resid+tanh(g)*v*mask; 3 resid+tanh(g)*(v+bias)
// ---------------------------------------------------------------------------
template <int EPI, typename TC>
__global__ __launch_bounds__(512, 2)
void gemm256p(const bf16* __restrict__ A, const bf16* __restrict__ Bt, TC* __restrict__ C,
              int K, int lda, int ldb, int ldc, float alpha,
              const float* __restrict__ resid,
              const float* __restrict__ bias,
              const float* __restrict__ gamma,
              const int* __restrict__ mask)
{
    __shared__ bf16 ldsA[3][16384];  // [buf][kc 0..7][row 0..255][8]
    __shared__ bf16 ldsB[3][8192];   // [buf][kc 0..7][row 0..127][8]

    int tid = threadIdx.x;
    int wave = tid >> 6, lane = tid & 63, quad = lane >> 4, l15 = lane & 15;
    int wm = (wave >> 1) * 64, wn = (wave & 1) * 64;
    int tileN = blockIdx.x * 128, tileM = blockIdx.y * 256;

    // staging coords: A c = r*512+tid (r=0..3), kc=c>>8, row=c&255
    //                 B c = r*512+tid (r=0..1), kc=c>>7, row=c&127
    const int cA0 = tid, cA1 = 512 + tid, cA2 = 1024 + tid, cA3 = 1536 + tid;
    const int cB0 = tid, cB1 = 512 + tid;
    const bf16* pA0 = A + (long)(tileM + (cA0 & 255)) * lda + (cA0 >> 8) * 8;
    const bf16* pA1 = A + (long)(tileM + (cA1 & 255)) * lda + (cA1 >> 8) * 8;
    const bf16* pA2 = A + (long)(tileM + (cA2 & 255)) * lda + (cA2 >> 8) * 8;
    const bf16* pA3 = A + (long)(tileM + (cA3 & 255)) * lda + (cA3 >> 8) * 8;
    const bf16* pB0 = Bt + (long)(tileN + (cB0 & 127)) * ldb + (cB0 >> 7) * 8;
    const bf16* pB1 = Bt + (long)(tileN + (cB1 & 127)) * ldb + (cB1 >> 7) * 8;

    f32x4 acc[4][4] = {};

    // fragment base offsets (elements); af stride per mi = 16 rows * 8 = 128
    const int abase = (quad * 256 + wm + l15) * 8;   // + ks*4*256*8
    const int bbase = (quad * 128 + wn + l15) * 8;   // + ks*4*128*8

    // prologue: tiles 0,1 -> bufs 0,1; wait tile 0 (vmcnt: 12 -> 6)
    {
        g2l16(&ldsA[0][cA0 * 8], pA0); g2l16(&ldsA[0][cA1 * 8], pA1);
        g2l16(&ldsA[0][cA2 * 8], pA2); g2l16(&ldsA[0][cA3 * 8], pA3);
        g2l16(&ldsB[0][cB0 * 8], pB0); g2l16(&ldsB[0][cB1 * 8], pB1);
        g2l16(&ldsA[1][cA0 * 8], pA0 + 64); g2l16(&ldsA[1][cA1 * 8], pA1 + 64);
        g2l16(&ldsA[1][cA2 * 8], pA2 + 64); g2l16(&ldsA[1][cA3 * 8], pA3 + 64);
        g2l16(&ldsB[1][cB0 * 8], pB0 + 64); g2l16(&ldsB[1][cB1 * 8], pB1 + 64);
        asm volatile("s_waitcnt vmcnt(6)" ::: "memory");
        asm volatile("s_barrier" ::: "memory");
    }

    int T = K >> 6, cb = 0;
    for (int t = 0; t < T; ++t) {
        int nb = cb + 2; if (nb >= 3) nb -= 3;
        long kn = (long)(t + 2) << 6;   // garbage for t >= T-2; never consumed
        const bf16* pa = ldsA[cb];
        const bf16* pb = ldsB[cb];

        // ---------------- phase 0 (ks = 0) ----------------
        g2l16(&ldsA[nb][cA0 * 8], pA0 + kn);
        g2l16(&ldsA[nb][cA1 * 8], pA1 + kn);
        g2l16(&ldsA[nb][cA2 * 8], pA2 + kn);
        {
            bf16x8 af[4], bq[4];
#pragma unroll
            for (int i = 0; i < 4; ++i) {
                af[i] = *(const bf16x8*)&pa[abase + i * 128];
                bq[i] = *(const bf16x8*)&pb[bbase + i * 128];
            }
            asm volatile("s_barrier" ::: "memory");
            asm volatile("s_waitcnt lgkmcnt(0)" ::: "memory");
            __builtin_amdgcn_sched_barrier(0);
            __builtin_amdgcn_s_setprio(1);
#pragma unroll
            for (int mi = 0; mi < 4; ++mi)
#pragma unroll
                for (int ni = 0; ni < 4; ++ni)
                    acc[mi][ni] = __builtin_amdgcn_mfma_f32_16x16x32_bf16(
                        af[mi], bq[ni], acc[mi][ni], 0, 0, 0);
            __builtin_amdgcn_s_setprio(0);
            asm volatile("s_barrier" ::: "memory");
        }

        // ---------------- phase 1 (ks = 1) ----------------
        g2l16(&ldsA[nb][cA3 * 8], pA3 + kn);
        g2l16(&ldsB[nb][cB0 * 8], pB0 + kn);
        g2l16(&ldsB[nb][cB1 * 8], pB1 + kn);
        {
            bf16x8 af[4], bq[4];
#pragma unroll
            for (int i = 0; i < 4; ++i) {
                af[i] = *(const bf16x8*)&pa[abase + 8192 + i * 128];  // ks=1: +4*256*8
                bq[i] = *(const bf16x8*)&pb[bbase + 4096 + i * 128];  // ks=1: +4*128*8
            }
            // wait tile t+1's 6 loads (12 outstanding -> 6); t+2's stay in flight
            asm volatile("s_waitcnt vmcnt(6)" ::: "memory");
            asm volatile("s_barrier" ::: "memory");
            asm volatile("s_waitcnt lgkmcnt(0)" ::: "memory");
            __builtin_amdgcn_sched_barrier(0);
            __builtin_amdgcn_s_setprio(1);
#pragma unroll
            for (int mi = 0; mi < 4; ++mi)
#pragma unroll
                for (int ni = 0; ni < 4; ++ni)
                    acc[mi][ni] = __builtin_amdgcn_mfma_f32_16x16x32_bf16(
                        af[mi], bq[ni], acc[mi][ni], 0, 0, 0);
            __builtin_amdgcn_s_setprio(0);
            asm volatile("s_barrier" ::: "memory");
        }
        cb = (cb == 2) ? 0 : cb + 1;
    }

    float gscale = 0.f;
    if (EPI == 2 || EPI == 3) gscale = tanhf(gamma[0]);
    float bb[4] = {};
    if (EPI == 1 || EPI == 3) {
#pragma unroll
        for (int ni = 0; ni < 4; ++ni)
            bb[ni] = bias[tileN + wn + ni * 16 + l15];
    }

#pragma unroll
    for (int mi = 0; mi < 4; ++mi) {
#pragma unroll
        for (int r = 0; r < 4; ++r) {
            int gm = tileM + wm + mi * 16 + quad * 4 + r;
            float rowmask = 1.f;
            if (EPI == 2) rowmask = mask[gm] ? 1.f : 0.f;
#pragma unroll
            for (int ni = 0; ni < 4; ++ni) {
                int gn = tileN + wn + ni * 16 + l15;
                float v = acc[mi][ni][r] * alpha;
                float r0;
                if (EPI == 0) {
                    r0 = v;
                } else if (EPI == 1) {
                    r0 = gelu_fast(v + bb[ni]);
                } else if (EPI == 2) {
                    float h = resid[(long)gm * ldc + gn];
                    r0 = h + gscale * v * rowmask;
                } else {
                    float h = resid[(long)gm * ldc + gn];
                    r0 = h + gscale * (v + bb[ni]);
                }
                C[(long)gm * ldc + gn] = (TC)r0;
            }
        }
    }
}

// ---------------------------------------------------------------------------
// Generic bf16 GEMM (128x128, 2-barrier): used for the small/batched attn ops.
// EPI: 0 plain*alpha.
// ---------------------------------------------------------------------------
template <int EPI, typename TC>
__global__ __launch_bounds__(256)
void gemm_bt(const bf16* __restrict__ A, const bf16* __restrict__ Bt, TC* __restrict__ C,
             int K, int lda, int ldb, int ldc,
             long sAo, long sAi, long sBo, long sBi, long sCo, long sCi, int zInner,
             float alpha,
             const float* __restrict__ resid,
             const float* __restrict__ bias,
             const float* __restrict__ gamma,
             const int* __restrict__ mask)
{
    int z = blockIdx.z;
    int zo = z / zInner, zi = z % zInner;
    A  += (long)zo * sAo + (long)zi * sAi;
    Bt += (long)zo * sBo + (long)zi * sBi;
    long cOff = (long)zo * sCo + (long)zi * sCi;

    int tileN = blockIdx.x * 128, tileM = blockIdx.y * 128;

    __shared__ bf16 As[8192];  // [kc][row][8]
    __shared__ bf16 Bs[8192];

    int tid = threadIdx.x;
    int wave = tid >> 6, lane = tid & 63, quad = lane >> 4, l15 = lane & 15;
    int wm = (wave >> 1) * 64, wn = (wave & 1) * 64;

    f32x4 acc[4][4] = {};

    for (int k0 = 0; k0 < K; k0 += 64) {
#pragma unroll
        for (int r = 0; r < 4; ++r) {
            int c = r * 256 + tid;
            int kc = c >> 7, row = c & 127;
            g2l16(&As[c * 8], A + (long)(tileM + row) * lda + (k0 + kc * 8));
            g2l16(&Bs[c * 8], Bt + (long)(tileN + row) * ldb + (k0 + kc * 8));
        }
        __syncthreads();
#pragma unroll
        for (int ks = 0; ks < 2; ++ks) {
            bf16x8 af[4], bq[4];
#pragma unroll
            for (int i = 0; i < 4; ++i) {
                af[i] = *(const bf16x8*)&As[((ks * 4 + quad) * 128 + wm + i * 16 + l15) * 8];
                bq[i] = *(const bf16x8*)&Bs[((ks * 4 + quad) * 128 + wn + i * 16 + l15) * 8];
            }
#pragma unroll
            for (int mi = 0; mi < 4; ++mi)
#pragma unroll
                for (int ni = 0; ni < 4; ++ni)
                    acc[mi][ni] = __builtin_amdgcn_mfma_f32_16x16x32_bf16(
                        af[mi], bq[ni], acc[mi][ni], 0, 0, 0);
        }
        __syncthreads();
    }

#pragma unroll
    for (int mi = 0; mi < 4; ++mi) {
#pragma unroll
        for (int r = 0; r < 4; ++r) {
            int gm = tileM + wm + mi * 16 + quad * 4 + r;
#pragma unroll
            for (int ni = 0; ni < 4; ++ni) {
                int gn = tileN + wn + ni * 16 + l15;
                float v = acc[mi][ni][r] * alpha;
                C[cOff + (long)gm * ldc + gn] = (TC)v;
            }
        }
    }
}

// ---------------------------------------------------------------------------
// LayerNorm over rows of 2048 (f32 in, f32 params, bf16 out). One row/block.
// ---------------------------------------------------------------------------
__global__ __launch_bounds__(256)
void ln_k(const float* __restrict__ x, const float* __restrict__ g, const float* __restrict__ b,
          bf16* __restrict__ out)
{
    long row = blockIdx.x;
    int tid = threadIdx.x;
    int wave = tid >> 6, lane = tid & 63;
    const float* px = x + row * 2048 + tid * 8;

    float4 a = *(const float4*)px;
    float4 c = *(const float4*)(px + 4);
    float f[8] = {a.x, a.y, a.z, a.w, c.x, c.y, c.z, c.w};

    float s = 0.f, s2 = 0.f;
#pragma unroll
    for (int j = 0; j < 8; ++j) { s += f[j]; s2 += f[j] * f[j]; }
    for (int o = 32; o; o >>= 1) { s += __shfl_xor(s, o, 64); s2 += __shfl_xor(s2, o, 64); }

    __shared__ float red[8];
    if (lane == 0) { red[wave] = s; red[4 + wave] = s2; }
    __syncthreads();
    s  = red[0] + red[1] + red[2] + red[3];
    s2 = red[4] + red[5] + red[6] + red[7];

    float mean = s * (1.f / 2048.f);
    float var  = s2 * (1.f / 2048.f) - mean * mean;
    float rstd = rsqrtf(var + 1e-5f);

    int col = tid * 8;
    bf16x8 o8;
#pragma unroll
    for (int j = 0; j < 8; ++j)
        o8[j] = (bf16)((f[j] - mean) * rstd * g[col + j] + b[col + j]);
    *(bf16x8*)(out + row * 2048 + tid * 8) = o8;
}

// ---------------------------------------------------------------------------
// Row softmax over 512 (in-place, bf16). One wave per row, 4 rows per block.
// ---------------------------------------------------------------------------
__global__ __launch_bounds__(256)
void softmax512(bf16* __restrict__ s)
{
    long row = (long)blockIdx.x * 4 + (threadIdx.x >> 6);
    int lane = threadIdx.x & 63;
    bf16* p = s + row * 512 + lane * 8;
    bf16x8 v = *(const bf16x8*)p;
    float f[8], mx = -1e30f;
#pragma unroll
    for (int j = 0; j < 8; ++j) { f[j] = (float)v[j]; mx = fmaxf(mx, f[j]); }
    for (int o = 32; o; o >>= 1) mx = fmaxf(mx, __shfl_xor(mx, o, 64));
    float sum = 0.f;
#pragma unroll
    for (int j = 0; j < 8; ++j) { f[j] = __expf(f[j] - mx); sum += f[j]; }
    for (int o = 32; o; o >>= 1) sum += __shfl_xor(sum, o, 64);
    float r = 1.f / sum;
    bf16x8 o8;
#pragma unroll
    for (int j = 0; j < 8; ++j) o8[j] = (bf16)(f[j] * r);
    *(bf16x8*)p = o8;
}

// ---------------------------------------------------------------------------
// Transpose f32 -> bf16: out[n][m] = (bf16)in[m][n]. Tile 32x32, block 256.
// ---------------------------------------------------------------------------
__global__ __launch_bounds__(256)
void transpose_cvt(const float* __restrict__ in, bf16* __restrict__ out, int ldi, int ldo)
{
    __shared__ float t[32][33];
    int tx = threadIdx.x & 31, ty = threadIdx.x >> 5;
    int n0 = blockIdx.x * 32, m0 = blockIdx.y * 32;
#pragma unroll
    for (int i = 0; i < 4; ++i)
        t[ty + i * 8][tx] = in[(long)(m0 + ty + i * 8) * ldi + n0 + tx];
    __syncthreads();
#pragma unroll
    for (int i = 0; i < 4; ++i)
        out[(long)(n0 + ty + i * 8) * ldo + m0 + tx] = (bf16)t[tx][ty + i * 8];
}

// ---------------------------------------------------------------------------
// Batched bf16 transpose (for V): out[n][m] = in[m][n]. Tile 32x32.
// ---------------------------------------------------------------------------
__global__ __launch_bounds__(256)
void transpose_k(const bf16* __restrict__ in, bf16* __restrict__ out,
                 int ldi, int ldo, long sIo, long sIi, long sOo, long sOi, int zInner)
{
    int z = blockIdx.z;
    in  += (long)(z / zInner) * sIo + (long)(z % zInner) * sIi;
    out += (long)(z / zInner) * sOo + (long)(z % zInner) * sOi;
    __shared__ bf16 t[32][33];
    int tx = threadIdx.x & 31, ty = threadIdx.x >> 5;
    int n0 = blockIdx.x * 32, m0 = blockIdx.y * 32;
#pragma unroll
    for (int i = 0; i < 4; ++i)
        t[ty + i * 8][tx] = in[(long)(m0 + ty + i * 8) * ldi + n0 + tx];
    __syncthreads();
#pragma unroll
    for (int i = 0; i < 4; ++i)
        out[(long)(n0 + ty + i * 8) * ldo + m0 + tx] = t[tx][ty + i * 8];
}

// f32 -> bf16 elementwise (for image_embeds). 4 elems/thread.
__global__ __launch_bounds__(256)
void cvt_k(const float* __restrict__ in, bf16* __restrict__ out)
{
    int i = (blockIdx.x * 256 + threadIdx.x) * 4;
    float4 v = *(const float4*)(in + i);
    out[i + 0] = (bf16)v.x;
    out[i + 1] = (bf16)v.y;
    out[i + 2] = (bf16)v.z;
    out[i + 3] = (bf16)v.w;
}

// ---------------------------------------------------------------------------
// Workspace layout (MiB offsets), peak 176 MiB:
//   0-32   : WqT(0) WkT(8) WvT(16) WoT(24)  -> later W1T(0-32)
//   32-48  : xln        -> later W2T low half
//   48-64  : q/attn_out -> later W2T high half
//   64-68  : kbuf   68-72: vbuf   72-76: vt   76-80: imgb
//   80-144 : sc (scores -> P -> h1)
//   144-176: x2 (f32)
// Tail garbage reads (<=256B past each GEMM operand) all land inside ws.
// ---------------------------------------------------------------------------
extern "C" void kernel_launch(void* const* d_in, const int* in_sizes, int n_in,
                              void* d_out, int out_size, void* d_ws, size_t ws_size,
                              hipStream_t stream)
{
    const float* hidden = (const float*)d_in[0];  // (2,2048,2048) f32
    const float* image  = (const float*)d_in[1];  // (2,8,64,2048) f32
    const int*   media  = (const int*)d_in[2];    // (2,2048)
    const float* Wq = (const float*)d_in[3];
    const float* Wk = (const float*)d_in[4];
    const float* Wv = (const float*)d_in[5];
    const float* Wo = (const float*)d_in[6];
    const float* lag = (const float*)d_in[7];
    const float* lab = (const float*)d_in[8];
    const float* lfg = (const float*)d_in[9];
    const float* lfb = (const float*)d_in[10];
    const float* W1 = (const float*)d_in[11];     // (2048, 8192)
    const float* b1 = (const float*)d_in[12];
    const float* W2 = (const float*)d_in[13];     // (8192, 2048)
    const float* b2 = (const float*)d_in[14];
    const float* ga = (const float*)d_in[15];
    const float* gf = (const float*)d_in[16];
    float* out = (float*)d_out;

    char* ws = (char*)d_ws;
    const size_t MB = 1ull << 20;
    bf16* WqT  = (bf16*)(ws + 0);
    bf16* WkT  = (bf16*)(ws + 8 * MB);
    bf16* WvT  = (bf16*)(ws + 16 * MB);
    bf16* WoT  = (bf16*)(ws + 24 * MB);
    bf16* W1T  = (bf16*)(ws + 0);         // reuses Wq..Wo region after attn
    bf16* W2T  = (bf16*)(ws + 32 * MB);   // reuses xln+q region after h1
    bf16* xln  = (bf16*)(ws + 32 * MB);
    bf16* q    = (bf16*)(ws + 48 * MB);
    bf16* kbuf = (bf16*)(ws + 64 * MB);
    bf16* vbuf = (bf16*)(ws + 68 * MB);
    bf16* vt   = (bf16*)(ws + 72 * MB);
    bf16* imgb = (bf16*)(ws + 76 * MB);
    bf16* sc   = (bf16*)(ws + 80 * MB);
    float* x2  = (float*)(ws + 144 * MB);

    const float SCALE = 0.08838834764831845f; // 128^-0.5
    dim3 blk(256);

    // f32 -> bf16 conversions / transposes
    transpose_cvt<<<dim3(64, 64, 1), blk, 0, stream>>>(Wq, WqT, 2048, 2048);
    transpose_cvt<<<dim3(64, 64, 1), blk, 0, stream>>>(Wk, WkT, 2048, 2048);
    transpose_cvt<<<dim3(64, 64, 1), blk, 0, stream>>>(Wv, WvT, 2048, 2048);
    transpose_cvt<<<dim3(64, 64, 1), blk, 0, stream>>>(Wo, WoT, 2048, 2048);
    cvt_k<<<2048, blk, 0, stream>>>(image, imgb);   // 2*512*2048 elems

    // x = LN(hidden)  (f32 in, bf16 out)
    ln_k<<<4096, blk, 0, stream>>>(hidden, lag, lab, xln);

    // q = x @ Wq   (M=4096, N=2048, K=2048) — phase-split 256x128
    gemm256p<0, bf16><<<dim3(16, 16, 1), dim3(512), 0, stream>>>(
        xln, WqT, q, 2048, 2048, 2048, 2048, 1.f,
        nullptr, nullptr, nullptr, nullptr);

    // k, v = image @ {Wk, Wv}  (M=1024, N=2048, K=2048; zi=0 -> k, zi=1 -> v)
    gemm_bt<0, bf16><<<dim3(16, 8, 2), blk, 0, stream>>>(
        imgb, WkT, kbuf, 2048, 2048, 2048, 2048,
        0, 0, 0, 4194304, 0, 2097152, 2, 1.f,
        nullptr, nullptr, nullptr, nullptr);

    // vt[b][h][d][kv] = v[b][kv][h*128+d]
    transpose_k<<<dim3(4, 16, 32), blk, 0, stream>>>(
        vbuf, vt, 2048, 512, 1048576, 128, 1048576, 65536, 16);

    // scores[b][h][s][kv] = SCALE * q_bh @ k_bh^T  (M=2048, N=512, K=128)
    gemm_bt<0, bf16><<<dim3(4, 16, 32), blk, 0, stream>>>(
        q, kbuf, sc, 128, 2048, 2048, 512,
        4194304, 128, 1048576, 128, 16777216, 1048576, 16, SCALE,
        nullptr, nullptr, nullptr, nullptr);

    // softmax over kv (in place)
    softmax512<<<16384, blk, 0, stream>>>(sc);

    // attn_out[b][s][h*128+d] = P_bh @ vt_bh^T  (M=2048, N=128, K=512)
    gemm_bt<0, bf16><<<dim3(1, 16, 32), blk, 0, stream>>>(
        sc, vt, q, 512, 512, 512, 2048,
        16777216, 1048576, 1048576, 65536, 4194304, 128, 16, 1.f,
        nullptr, nullptr, nullptr, nullptr);

    // x2 = hidden + tanh(ga) * (attn_out @ Wo) * mask   (f32 out)
    gemm256p<2, float><<<dim3(16, 16, 1), dim3(512), 0, stream>>>(
        q, WoT, x2, 2048, 2048, 2048, 2048, 1.f,
        hidden, nullptr, ga, media);

    // FFN weights (reuse dead regions)
    transpose_cvt<<<dim3(256, 64, 1), blk, 0, stream>>>(W1, W1T, 8192, 2048);

    // ln2 = LN(x2)
    ln_k<<<4096, blk, 0, stream>>>(x2, lfg, lfb, xln);

    // h1 = gelu(ln2 @ W1 + b1)  (M=4096, N=8192, K=2048)
    gemm256p<1, bf16><<<dim3(64, 16, 1), dim3(512), 0, stream>>>(
        xln, W1T, sc, 2048, 2048, 2048, 8192, 1.f,
        nullptr, b1, nullptr, nullptr);

    // W2T after h1 (xln, q dead now)
    transpose_cvt<<<dim3(64, 256, 1), blk, 0, stream>>>(W2, W2T, 2048, 8192);

    // out = x2 + tanh(gf) * (h1 @ W2 + b2)  (M=4096, N=2048, K=8192, f32 out)
    gemm256p<3, float><<<dim3(16, 16, 1), dim3(512), 0, stream>>>(
        sc, W2T, out, 8192, 8192, 8192, 2048, 1.f,
        x2, b2, gf, nullptr);
}

// Round 4
// 1128.414 us; speedup vs baseline: 1.1551x; 1.1551x over previous
//
#include <hip/hip_runtime.h>
#include <math.h>
#include <stdint.h>

typedef __bf16 bf16;
typedef __bf16 bf16x8 __attribute__((ext_vector_type(8)));
typedef float f32x4 __attribute__((ext_vector_type(4)));

#define DEV __device__ __forceinline__

// async global->LDS, 16B per lane. LDS dest must be wave-uniform base + lane*16.
DEV void g2l16(void* lds, const void* g) {
    __builtin_amdgcn_global_load_lds(
        (const __attribute__((address_space(1))) uint32_t*)g,
        (__attribute__((address_space(3))) uint32_t*)lds,
        16, 0, 0);
}

// Fast gelu: x * sigmoid(1.5957691216*(x + 0.044715 x^3)).
DEV float gelu_fast(float x) {
    float u = -1.5957691216f * __builtin_fmaf(0.044715f * x, x * x, x);
    return x * __builtin_amdgcn_rcpf(1.f + __expf(u));
}

// ---------------------------------------------------------------------------
// gemm_p2: 256x128-tile GEMM, BK=32, 2-deep counted pipeline, 2 blocks/CU.
// C = alpha * A @ Bt^T (+ epilogue). 512 threads = 8 waves (4M x 2N), each
// wave 64x64 via 4x4 mfma_f32_16x16x32_bf16 (16 MFMA/iter).
// LDS 48KB (2 x (A 16KB + B 8KB)) -> 2 blocks/CU: cross-block TLP fills the
// barrier/LDS-latency stalls (the m97 mechanism; r3's 1-block/CU lockstep
// had none and regressed). Counted vmcnt: per iter, stage tile t+1 (3 loads),
// then s_waitcnt vmcnt(3) waits ONLY tile t's 3 loads; t+1's stay in flight
// across both barriers (never drained to 0 in the loop). Raw s_barrier (no
// __syncthreads -> no vmcnt(0) drain). ds_reads are compiler IR loads, so
// lgkm waits before MFMA are compiler-inserted (no sched_barrier pinning).
// Race-freedom: buf[nb] re-staged at iter t holds tile t-1, dead since iter
// t-1's closing barrier; vmcnt FIFO makes the 3-count exact; one compute
// phase (~1000cy) covers L2 (~200cy) and most HBM (~900cy) latency.
// Tail: stage(T) reads <=64B past row ends (into adjacent ws regions), never
// consumed.
// EPI: 0 plain*alpha; 1 bias+gelu; 2 resid+tanh(g)*v*mask; 3 resid+tanh(g)*(v+bias)
// ---------------------------------------------------------------------------
template <int EPI, typename TC>
__global__ __launch_bounds__(512, 2)
void gemm_p2(const bf16* __restrict__ A, const bf16* __restrict__ Bt, TC* __restrict__ C,
             int K, int lda, int ldb, int ldc, float alpha,
             const float* __restrict__ resid,
             const float* __restrict__ bias,
             const float* __restrict__ gamma,
             const int* __restrict__ mask)
{
    __shared__ bf16 ldsA[2][8192];   // [buf][kc 0..3][row 0..255][8]
    __shared__ bf16 ldsB[2][4096];   // [buf][kc 0..3][row 0..127][8]

    int tid = threadIdx.x;
    int wave = tid >> 6, lane = tid & 63, quad = lane >> 4, l15 = lane & 15;
    int wm = (wave >> 1) * 64, wn = (wave & 1) * 64;
    int tileN = blockIdx.x * 128, tileM = blockIdx.y * 256;

    // staging coords: A entries c=tid, 512+tid (kc=c>>8, row=c&255);
    //                 B entry  c=tid (kc=c>>7, row=c&127). 16B per entry.
    const int cA0 = tid, cA1 = 512 + tid, cB0 = tid;
    const bf16* pA0 = A + (long)(tileM + (cA0 & 255)) * lda + (cA0 >> 8) * 8;
    const bf16* pA1 = A + (long)(tileM + (cA1 & 255)) * lda + (cA1 >> 8) * 8;
    const bf16* pB0 = Bt + (long)(tileN + (cB0 & 127)) * ldb + (cB0 >> 7) * 8;

    f32x4 acc[4][4] = {};
    const int abase = (quad * 256 + wm + l15) * 8;   // + mi*16 rows => +mi*128 elems
    const int bbase = (quad * 128 + wn + l15) * 8;

    // prologue: tile 0 -> buf 0 (3 loads in flight)
    g2l16(&ldsA[0][cA0 * 8], pA0);
    g2l16(&ldsA[0][cA1 * 8], pA1);
    g2l16(&ldsB[0][cB0 * 8], pB0);

    int T = K >> 5;
    for (int t = 0; t < T; ++t) {
        int cb = t & 1, nb = cb ^ 1;
        long kn = (long)(t + 1) << 5;
        // stage tile t+1 into buf nb (holds tile t-1, dead since t-1's close)
        g2l16(&ldsA[nb][cA0 * 8], pA0 + kn);
        g2l16(&ldsA[nb][cA1 * 8], pA1 + kn);
        g2l16(&ldsB[nb][cB0 * 8], pB0 + kn);
        // wait tile t's 3 loads (6 outstanding -> 3); tile t+1's stay in flight
        asm volatile("s_waitcnt vmcnt(3)\n\ts_barrier" ::: "memory");

        const bf16* pa = ldsA[cb];
        const bf16* pb = ldsB[cb];
        bf16x8 af[4], bq[4];
#pragma unroll
        for (int i = 0; i < 4; ++i) {
            af[i] = *(const bf16x8*)&pa[abase + i * 128];
            bq[i] = *(const bf16x8*)&pb[bbase + i * 128];
        }
        __builtin_amdgcn_s_setprio(1);
#pragma unroll
        for (int mi = 0; mi < 4; ++mi)
#pragma unroll
            for (int ni = 0; ni < 4; ++ni)
                acc[mi][ni] = __builtin_amdgcn_mfma_f32_16x16x32_bf16(
                    af[mi], bq[ni], acc[mi][ni], 0, 0, 0);
        __builtin_amdgcn_s_setprio(0);
        asm volatile("s_barrier" ::: "memory");   // all waves done with buf cb
    }

    float gscale = 0.f;
    if (EPI == 2 || EPI == 3) gscale = tanhf(gamma[0]);
    float bb[4] = {};
    if (EPI == 1 || EPI == 3) {
#pragma unroll
        for (int ni = 0; ni < 4; ++ni)
            bb[ni] = bias[tileN + wn + ni * 16 + l15];
    }

#pragma unroll
    for (int mi = 0; mi < 4; ++mi) {
#pragma unroll
        for (int r = 0; r < 4; ++r) {
            int gm = tileM + wm + mi * 16 + quad * 4 + r;
            float rowmask = 1.f;
            if (EPI == 2) rowmask = mask[gm] ? 1.f : 0.f;
#pragma unroll
            for (int ni = 0; ni < 4; ++ni) {
                int gn = tileN + wn + ni * 16 + l15;
                float v = acc[mi][ni][r] * alpha;
                float r0;
                if (EPI == 0) {
                    r0 = v;
                } else if (EPI == 1) {
                    r0 = gelu_fast(v + bb[ni]);
                } else if (EPI == 2) {
                    float h = resid[(long)gm * ldc + gn];
                    r0 = h + gscale * v * rowmask;
                } else {
                    float h = resid[(long)gm * ldc + gn];
                    r0 = h + gscale * (v + bb[ni]);
                }
                C[(long)gm * ldc + gn] = (TC)r0;
            }
        }
    }
}

// ---------------------------------------------------------------------------
// Deep-pipelined 256x256 GEMM for h1: C = gelu(A @ Bt^T + bias), bf16 out.
// BK=32, 3-deep LDS buffers (96KB), counted vmcnt(8). Measured 620 TF (r2).
// ---------------------------------------------------------------------------
__global__ __launch_bounds__(512, 2)
void gemm256_h1(const bf16* __restrict__ A, const bf16* __restrict__ Bt,
                bf16* __restrict__ C, int K, int lda, int ldb, int ldc,
                const float* __restrict__ bias)
{
    __shared__ bf16 lds[3][2][8192];   // [buf][A/B][kc*256+row][8] 16KB each

    int tid = threadIdx.x;
    int wave = tid >> 6, lane = tid & 63, quad = lane >> 4, l15 = lane & 15;
    int wm = (wave >> 2) * 128, wn = (wave & 3) * 64;
    int tileN = blockIdx.x * 256, tileM = blockIdx.y * 256;

    int c0 = tid, c1 = 512 + tid;
    int kc0 = c0 >> 8, row0 = c0 & 255;
    int kc1 = c1 >> 8, row1 = c1 & 255;
    const bf16* A0 = A + (long)(tileM + row0) * lda + kc0 * 8;
    const bf16* A1 = A + (long)(tileM + row1) * lda + kc1 * 8;
    const bf16* B0 = Bt + (long)(tileN + row0) * ldb + kc0 * 8;
    const bf16* B1 = Bt + (long)(tileN + row1) * ldb + kc1 * 8;

    f32x4 acc[8][4] = {};

    int aoff = (quad * 256 + wm + l15) * 8;
    int boff = (quad * 256 + wn + l15) * 8;

    auto stage = [&](int t, int b) {
        int k0 = t * 32;
        g2l16(&lds[b][0][c0 * 8], A0 + k0);
        g2l16(&lds[b][0][c1 * 8], A1 + k0);
        g2l16(&lds[b][1][c0 * 8], B0 + k0);
        g2l16(&lds[b][1][c1 * 8], B1 + k0);
    };

    stage(0, 0);
    stage(1, 1);

    int T = K >> 5;
    int cb = 0;
    for (int t = 0; t < T; ++t) {
        int nb = cb + 2; if (nb >= 3) nb -= 3;
        stage(t + 2, nb);   // garbage for t >= T-2; never consumed

        asm volatile("s_waitcnt vmcnt(8)\n\ts_barrier" ::: "memory");

        const bf16* pA = &lds[cb][0][0];
        const bf16* pB = &lds[cb][1][0];
        bf16x8 af[8], bq[4];
#pragma unroll
        for (int mi = 0; mi < 8; ++mi)
            af[mi] = *(const bf16x8*)&pA[aoff + mi * 128];
#pragma unroll
        for (int ni = 0; ni < 4; ++ni)
            bq[ni] = *(const bf16x8*)&pB[boff + ni * 128];

        __builtin_amdgcn_s_setprio(1);
#pragma unroll
        for (int mi = 0; mi < 8; ++mi)
#pragma unroll
            for (int ni = 0; ni < 4; ++ni)
                acc[mi][ni] = __builtin_amdgcn_mfma_f32_16x16x32_bf16(
                    af[mi], bq[ni], acc[mi][ni], 0, 0, 0);
        __builtin_amdgcn_s_setprio(0);

        asm volatile("s_barrier" ::: "memory");
        cb = (cb == 2) ? 0 : cb + 1;
    }

    float bb[4];
#pragma unroll
    for (int ni = 0; ni < 4; ++ni)
        bb[ni] = bias[tileN + wn + ni * 16 + l15];

#pragma unroll
    for (int mi = 0; mi < 8; ++mi) {
#pragma unroll
        for (int r = 0; r < 4; ++r) {
            int gm = tileM + wm + mi * 16 + quad * 4 + r;
#pragma unroll
            for (int ni = 0; ni < 4; ++ni) {
                int gn = tileN + wn + ni * 16 + l15;
                float x = acc[mi][ni][r] + bb[ni];
                C[(long)gm * ldc + gn] = (bf16)gelu_fast(x);
            }
        }
    }
}

// ---------------------------------------------------------------------------
// Generic bf16 GEMM (128x128, 2-barrier): used for the small/batched attn ops.
// ---------------------------------------------------------------------------
template <int EPI, typename TC>
__global__ __launch_bounds__(256)
void gemm_bt(const bf16* __restrict__ A, const bf16* __restrict__ Bt, TC* __restrict__ C,
             int K, int lda, int ldb, int ldc,
             long sAo, long sAi, long sBo, long sBi, long sCo, long sCi, int zInner,
             float alpha,
             const float* __restrict__ resid,
             const float* __restrict__ bias,
             const float* __restrict__ gamma,
             const int* __restrict__ mask)
{
    int z = blockIdx.z;
    int zo = z / zInner, zi = z % zInner;
    A  += (long)zo * sAo + (long)zi * sAi;
    Bt += (long)zo * sBo + (long)zi * sBi;
    long cOff = (long)zo * sCo + (long)zi * sCi;

    int tileN = blockIdx.x * 128, tileM = blockIdx.y * 128;

    __shared__ bf16 As[8192];  // [kc][row][8]
    __shared__ bf16 Bs[8192];

    int tid = threadIdx.x;
    int wave = tid >> 6, lane = tid & 63, quad = lane >> 4, l15 = lane & 15;
    int wm = (wave >> 1) * 64, wn = (wave & 1) * 64;

    f32x4 acc[4][4] = {};

    for (int k0 = 0; k0 < K; k0 += 64) {
#pragma unroll
        for (int r = 0; r < 4; ++r) {
            int c = r * 256 + tid;
            int kc = c >> 7, row = c & 127;
            g2l16(&As[c * 8], A + (long)(tileM + row) * lda + (k0 + kc * 8));
            g2l16(&Bs[c * 8], Bt + (long)(tileN + row) * ldb + (k0 + kc * 8));
        }
        __syncthreads();
#pragma unroll
        for (int ks = 0; ks < 2; ++ks) {
            bf16x8 af[4], bq[4];
#pragma unroll
            for (int i = 0; i < 4; ++i) {
                af[i] = *(const bf16x8*)&As[((ks * 4 + quad) * 128 + wm + i * 16 + l15) * 8];
                bq[i] = *(const bf16x8*)&Bs[((ks * 4 + quad) * 128 + wn + i * 16 + l15) * 8];
            }
#pragma unroll
            for (int mi = 0; mi < 4; ++mi)
#pragma unroll
                for (int ni = 0; ni < 4; ++ni)
                    acc[mi][ni] = __builtin_amdgcn_mfma_f32_16x16x32_bf16(
                        af[mi], bq[ni], acc[mi][ni], 0, 0, 0);
        }
        __syncthreads();
    }

#pragma unroll
    for (int mi = 0; mi < 4; ++mi) {
#pragma unroll
        for (int r = 0; r < 4; ++r) {
            int gm = tileM + wm + mi * 16 + quad * 4 + r;
#pragma unroll
            for (int ni = 0; ni < 4; ++ni) {
                int gn = tileN + wn + ni * 16 + l15;
                float v = acc[mi][ni][r] * alpha;
                C[cOff + (long)gm * ldc + gn] = (TC)v;
            }
        }
    }
}

// ---------------------------------------------------------------------------
// LayerNorm over rows of 2048 (f32 in, f32 params, bf16 out). One row/block.
// ---------------------------------------------------------------------------
__global__ __launch_bounds__(256)
void ln_k(const float* __restrict__ x, const float* __restrict__ g, const float* __restrict__ b,
          bf16* __restrict__ out)
{
    long row = blockIdx.x;
    int tid = threadIdx.x;
    int wave = tid >> 6, lane = tid & 63;
    const float* px = x + row * 2048 + tid * 8;

    float4 a = *(const float4*)px;
    float4 c = *(const float4*)(px + 4);
    float f[8] = {a.x, a.y, a.z, a.w, c.x, c.y, c.z, c.w};

    float s = 0.f, s2 = 0.f;
#pragma unroll
    for (int j = 0; j < 8; ++j) { s += f[j]; s2 += f[j] * f[j]; }
    for (int o = 32; o; o >>= 1) { s += __shfl_xor(s, o, 64); s2 += __shfl_xor(s2, o, 64); }

    __shared__ float red[8];
    if (lane == 0) { red[wave] = s; red[4 + wave] = s2; }
    __syncthreads();
    s  = red[0] + red[1] + red[2] + red[3];
    s2 = red[4] + red[5] + red[6] + red[7];

    float mean = s * (1.f / 2048.f);
    float var  = s2 * (1.f / 2048.f) - mean * mean;
    float rstd = rsqrtf(var + 1e-5f);

    int col = tid * 8;
    bf16x8 o8;
#pragma unroll
    for (int j = 0; j < 8; ++j)
        o8[j] = (bf16)((f[j] - mean) * rstd * g[col + j] + b[col + j]);
    *(bf16x8*)(out + row * 2048 + tid * 8) = o8;
}

// ---------------------------------------------------------------------------
// Row softmax over 512 (in-place, bf16). One wave per row, 4 rows per block.
// ---------------------------------------------------------------------------
__global__ __launch_bounds__(256)
void softmax512(bf16* __restrict__ s)
{
    long row = (long)blockIdx.x * 4 + (threadIdx.x >> 6);
    int lane = threadIdx.x & 63;
    bf16* p = s + row * 512 + lane * 8;
    bf16x8 v = *(const bf16x8*)p;
    float f[8], mx = -1e30f;
#pragma unroll
    for (int j = 0; j < 8; ++j) { f[j] = (float)v[j]; mx = fmaxf(mx, f[j]); }
    for (int o = 32; o; o >>= 1) mx = fmaxf(mx, __shfl_xor(mx, o, 64));
    float sum = 0.f;
#pragma unroll
    for (int j = 0; j < 8; ++j) { f[j] = __expf(f[j] - mx); sum += f[j]; }
    for (int o = 32; o; o >>= 1) sum += __shfl_xor(sum, o, 64);
    float r = 1.f / sum;
    bf16x8 o8;
#pragma unroll
    for (int j = 0; j < 8; ++j) o8[j] = (bf16)(f[j] * r);
    *(bf16x8*)p = o8;
}

// ---------------------------------------------------------------------------
// Transpose f32 -> bf16: out[n][m] = (bf16)in[m][n]. Tile 32x32, block 256.
// ---------------------------------------------------------------------------
__global__ __launch_bounds__(256)
void transpose_cvt(const float* __restrict__ in, bf16* __restrict__ out, int ldi, int ldo)
{
    __shared__ float t[32][33];
    int tx = threadIdx.x & 31, ty = threadIdx.x >> 5;
    int n0 = blockIdx.x * 32, m0 = blockIdx.y * 32;
#pragma unroll
    for (int i = 0; i < 4; ++i)
        t[ty + i * 8][tx] = in[(long)(m0 + ty + i * 8) * ldi + n0 + tx];
    __syncthreads();
#pragma unroll
    for (int i = 0; i < 4; ++i)
        out[(long)(n0 + ty + i * 8) * ldo + m0 + tx] = (bf16)t[tx][ty + i * 8];
}

// ---------------------------------------------------------------------------
// Batched bf16 transpose (for V): out[n][m] = in[m][n]. Tile 32x32.
// ---------------------------------------------------------------------------
__global__ __launch_bounds__(256)
void transpose_k(const bf16* __restrict__ in, bf16* __restrict__ out,
                 int ldi, int ldo, long sIo, long sIi, long sOo, long sOi, int zInner)
{
    int z = blockIdx.z;
    in  += (long)(z / zInner) * sIo + (long)(z % zInner) * sIi;
    out += (long)(z / zInner) * sOo + (long)(z % zInner) * sOi;
    __shared__ bf16 t[32][33];
    int tx = threadIdx.x & 31, ty = threadIdx.x >> 5;
    int n0 = blockIdx.x * 32, m0 = blockIdx.y * 32;
#pragma unroll
    for (int i = 0; i < 4; ++i)
        t[ty + i * 8][tx] = in[(long)(m0 + ty + i * 8) * ldi + n0 + tx];
    __syncthreads();
#pragma unroll
    for (int i = 0; i < 4; ++i)
        out[(long)(n0 + ty + i * 8) * ldo + m0 + tx] = t[tx][ty + i * 8];
}

// f32 -> bf16 elementwise (for image_embeds). 4 elems/thread.
__global__ __launch_bounds__(256)
void cvt_k(const float* __restrict__ in, bf16* __restrict__ out)
{
    int i = (blockIdx.x * 256 + threadIdx.x) * 4;
    float4 v = *(const float4*)(in + i);
    out[i + 0] = (bf16)v.x;
    out[i + 1] = (bf16)v.y;
    out[i + 2] = (bf16)v.z;
    out[i + 3] = (bf16)v.w;
}

// ---------------------------------------------------------------------------
// Workspace layout (MiB offsets), peak 176 MiB:
//   0-32   : WqT(0) WkT(8) WvT(16) WoT(24)  -> later W1T(0-32)
//   32-48  : xln        -> later W2T low half
//   48-64  : q/attn_out -> later W2T high half
//   64-68  : kbuf   68-72: vbuf   72-76: vt   76-80: imgb
//   80-144 : sc (scores -> P -> h1)
//   144-176: x2 (f32)
// Tail garbage reads (<=256B past each GEMM operand) all land inside ws.
// ---------------------------------------------------------------------------
extern "C" void kernel_launch(void* const* d_in, const int* in_sizes, int n_in,
                              void* d_out, int out_size, void* d_ws, size_t ws_size,
                              hipStream_t stream)
{
    const float* hidden = (const float*)d_in[0];  // (2,2048,2048) f32
    const float* image  = (const float*)d_in[1];  // (2,8,64,2048) f32
    const int*   media  = (const int*)d_in[2];    // (2,2048)
    const float* Wq = (const float*)d_in[3];
    const float* Wk = (const float*)d_in[4];
    const float* Wv = (const float*)d_in[5];
    const float* Wo = (const float*)d_in[6];
    const float* lag = (const float*)d_in[7];
    const float* lab = (const float*)d_in[8];
    const float* lfg = (const float*)d_in[9];
    const float* lfb = (const float*)d_in[10];
    const float* W1 = (const float*)d_in[11];     // (2048, 8192)
    const float* b1 = (const float*)d_in[12];
    const float* W2 = (const float*)d_in[13];     // (8192, 2048)
    const float* b2 = (const float*)d_in[14];
    const float* ga = (const float*)d_in[15];
    const float* gf = (const float*)d_in[16];
    float* out = (float*)d_out;

    char* ws = (char*)d_ws;
    const size_t MB = 1ull << 20;
    bf16* WqT  = (bf16*)(ws + 0);
    bf16* WkT  = (bf16*)(ws + 8 * MB);
    bf16* WvT  = (bf16*)(ws + 16 * MB);
    bf16* WoT  = (bf16*)(ws + 24 * MB);
    bf16* W1T  = (bf16*)(ws + 0);         // reuses Wq..Wo region after attn
    bf16* W2T  = (bf16*)(ws + 32 * MB);   // reuses xln+q region after h1
    bf16* xln  = (bf16*)(ws + 32 * MB);
    bf16* q    = (bf16*)(ws + 48 * MB);
    bf16* kbuf = (bf16*)(ws + 64 * MB);
    bf16* vbuf = (bf16*)(ws + 68 * MB);
    bf16* vt   = (bf16*)(ws + 72 * MB);
    bf16* imgb = (bf16*)(ws + 76 * MB);
    bf16* sc   = (bf16*)(ws + 80 * MB);
    float* x2  = (float*)(ws + 144 * MB);

    const float SCALE = 0.08838834764831845f; // 128^-0.5
    dim3 blk(256);

    // f32 -> bf16 conversions / transposes
    transpose_cvt<<<dim3(64, 64, 1), blk, 0, stream>>>(Wq, WqT, 2048, 2048);
    transpose_cvt<<<dim3(64, 64, 1), blk, 0, stream>>>(Wk, WkT, 2048, 2048);
    transpose_cvt<<<dim3(64, 64, 1), blk, 0, stream>>>(Wv, WvT, 2048, 2048);
    transpose_cvt<<<dim3(64, 64, 1), blk, 0, stream>>>(Wo, WoT, 2048, 2048);
    cvt_k<<<2048, blk, 0, stream>>>(image, imgb);   // 2*512*2048 elems

    // x = LN(hidden)  (f32 in, bf16 out)
    ln_k<<<4096, blk, 0, stream>>>(hidden, lag, lab, xln);

    // q = x @ Wq   (M=4096, N=2048, K=2048) — 256x128 2-deep pipelined
    gemm_p2<0, bf16><<<dim3(16, 16, 1), dim3(512), 0, stream>>>(
        xln, WqT, q, 2048, 2048, 2048, 2048, 1.f,
        nullptr, nullptr, nullptr, nullptr);

    // k, v = image @ {Wk, Wv}  (M=1024, N=2048, K=2048; zi=0 -> k, zi=1 -> v)
    gemm_bt<0, bf16><<<dim3(16, 8, 2), blk, 0, stream>>>(
        imgb, WkT, kbuf, 2048, 2048, 2048, 2048,
        0, 0, 0, 4194304, 0, 2097152, 2, 1.f,
        nullptr, nullptr, nullptr, nullptr);

    // vt[b][h][d][kv] = v[b][kv][h*128+d]
    transpose_k<<<dim3(4, 16, 32), blk, 0, stream>>>(
        vbuf, vt, 2048, 512, 1048576, 128, 1048576, 65536, 16);

    // scores[b][h][s][kv] = SCALE * q_bh @ k_bh^T  (M=2048, N=512, K=128)
    gemm_bt<0, bf16><<<dim3(4, 16, 32), blk, 0, stream>>>(
        q, kbuf, sc, 128, 2048, 2048, 512,
        4194304, 128, 1048576, 128, 16777216, 1048576, 16, SCALE,
        nullptr, nullptr, nullptr, nullptr);

    // softmax over kv (in place)
    softmax512<<<16384, blk, 0, stream>>>(sc);

    // attn_out[b][s][h*128+d] = P_bh @ vt_bh^T  (M=2048, N=128, K=512)
    gemm_bt<0, bf16><<<dim3(1, 16, 32), blk, 0, stream>>>(
        sc, vt, q, 512, 512, 512, 2048,
        16777216, 1048576, 1048576, 65536, 4194304, 128, 16, 1.f,
        nullptr, nullptr, nullptr, nullptr);

    // x2 = hidden + tanh(ga) * (attn_out @ Wo) * mask   (f32 out)
    gemm_p2<2, float><<<dim3(16, 16, 1), dim3(512), 0, stream>>>(
        q, WoT, x2, 2048, 2048, 2048, 2048, 1.f,
        hidden, nullptr, ga, media);

    // FFN weights (reuse dead regions)
    transpose_cvt<<<dim3(256, 64, 1), blk, 0, stream>>>(W1, W1T, 8192, 2048);

    // ln2 = LN(x2)
    ln_k<<<4096, blk, 0, stream>>>(x2, lfg, lfb, xln);

    // h1 = gelu(ln2 @ W1 + b1)  (M=4096, N=8192, K=2048) — r2 template (620 TF)
    gemm256_h1<<<dim3(32, 16, 1), dim3(512), 0, stream>>>(
        xln, W1T, sc, 2048, 2048, 2048, 8192, b1);

    // W2T after h1 (xln, q dead now)
    transpose_cvt<<<dim3(64, 256, 1), blk, 0, stream>>>(W2, W2T, 2048, 8192);

    // out = x2 + tanh(gf) * (h1 @ W2 + b2)  (M=4096, N=2048, K=8192, f32 out)
    gemm_p2<3, float><<<dim3(16, 16, 1), dim3(512), 0, stream>>>(
        sc, W2T, out, 8192, 8192, 8192, 2048, 1.f,
        x2, b2, gf, nullptr);
}

// Round 5
// 1027.422 us; speedup vs baseline: 1.2686x; 1.0983x over previous
//
#include <hip/hip_runtime.h>
#include <math.h>
#include <stdint.h>

typedef __bf16 bf16;
typedef __bf16 bf16x8 __attribute__((ext_vector_type(8)));
typedef float f32x4 __attribute__((ext_vector_type(4)));

#define DEV __device__ __forceinline__

// async global->LDS, 16B per lane. LDS dest must be wave-uniform base + lane*16.
DEV void g2l16(void* lds, const void* g) {
    __builtin_amdgcn_global_load_lds(
        (const __attribute__((address_space(1))) uint32_t*)g,
        (__attribute__((address_space(3))) uint32_t*)lds,
        16, 0, 0);
}

// Fast gelu: x * sigmoid(1.5957691216*(x + 0.044715 x^3)).
DEV float gelu_fast(float x) {
    float u = -1.5957691216f * __builtin_fmaf(0.044715f * x, x * x, x);
    return x * __builtin_amdgcn_rcpf(1.f + __expf(u));
}

// XCD-chunked block swizzle (T1). HW round-robins original flat id -> XCD
// (id % 8); remapping logical tile = (id%8)*q + id/8 gives each XCD a
// CONTIGUOUS chunk of tiles -> consecutive blocks on one XCD share operand
// panels in that XCD's private L2. Bijective iff nwg % 8 == 0 (guarded).
DEV void xcd_swizzle(int& bx, int& by, int& bz) {
    int gx = gridDim.x, gy = gridDim.y, gz = gridDim.z;
    int nwg = gx * gy * gz;
    if (nwg & 7) return;
    long flat = ((long)bz * gy + by) * gx + bx;
    long q = nwg >> 3;
    long sw = (flat & 7) * q + (flat >> 3);
    bx = (int)(sw % gx);
    long t = sw / gx;
    by = (int)(t % gy);
    bz = (int)(t / gy);
}

// ---------------------------------------------------------------------------
// Generic bf16 GEMM: C = alpha * A @ Bt^T (+ epilogue). 128x128 tile, BK=64,
// 256 threads = 4 waves (2x2), each wave 64x64 via 4x4 mfma_f32_16x16x32_bf16.
// LDS k-chunked [kc][row][8]: conflict-free ds_read_b128, g2l16 staging.
// Measured 445-458 TF at 2.5 blocks/CU — best per-shape structure so far for
// N<=2048 grids. XCD-chunked swizzle for L2 panel reuse.
// EPI: 0 plain*alpha; 1 bias+gelu; 2 resid+tanh(g)*v*mask; 3 resid+tanh(g)*(v+bias)
// ---------------------------------------------------------------------------
template <int EPI, typename TC>
__global__ __launch_bounds__(256)
void gemm_bt(const bf16* __restrict__ A, const bf16* __restrict__ Bt, TC* __restrict__ C,
             int K, int lda, int ldb, int ldc,
             long sAo, long sAi, long sBo, long sBi, long sCo, long sCi, int zInner,
             float alpha,
             const float* __restrict__ resid,
             const float* __restrict__ bias,
             const float* __restrict__ gamma,
             const int* __restrict__ mask)
{
    int bx = blockIdx.x, by = blockIdx.y, bz = blockIdx.z;
    xcd_swizzle(bx, by, bz);

    int zo = bz / zInner, zi = bz % zInner;
    A  += (long)zo * sAo + (long)zi * sAi;
    Bt += (long)zo * sBo + (long)zi * sBi;
    long cOff = (long)zo * sCo + (long)zi * sCi;

    int tileN = bx * 128, tileM = by * 128;

    __shared__ bf16 As[8192];  // [kc][row][8]
    __shared__ bf16 Bs[8192];

    int tid = threadIdx.x;
    int wave = tid >> 6, lane = tid & 63, quad = lane >> 4, l15 = lane & 15;
    int wm = (wave >> 1) * 64, wn = (wave & 1) * 64;

    f32x4 acc[4][4] = {};

    for (int k0 = 0; k0 < K; k0 += 64) {
#pragma unroll
        for (int r = 0; r < 4; ++r) {
            int c = r * 256 + tid;
            int kc = c >> 7, row = c & 127;
            g2l16(&As[c * 8], A + (long)(tileM + row) * lda + (k0 + kc * 8));
            g2l16(&Bs[c * 8], Bt + (long)(tileN + row) * ldb + (k0 + kc * 8));
        }
        __syncthreads();
#pragma unroll
        for (int ks = 0; ks < 2; ++ks) {
            bf16x8 af[4], bq[4];
#pragma unroll
            for (int i = 0; i < 4; ++i) {
                af[i] = *(const bf16x8*)&As[((ks * 4 + quad) * 128 + wm + i * 16 + l15) * 8];
                bq[i] = *(const bf16x8*)&Bs[((ks * 4 + quad) * 128 + wn + i * 16 + l15) * 8];
            }
#pragma unroll
            for (int mi = 0; mi < 4; ++mi)
#pragma unroll
                for (int ni = 0; ni < 4; ++ni)
                    acc[mi][ni] = __builtin_amdgcn_mfma_f32_16x16x32_bf16(
                        af[mi], bq[ni], acc[mi][ni], 0, 0, 0);
        }
        __syncthreads();
    }

    float gscale = 0.f;
    if (EPI == 2 || EPI == 3) gscale = tanhf(gamma[0]);

    float bb[4] = {};
    if (EPI == 1 || EPI == 3) {
#pragma unroll
        for (int ni = 0; ni < 4; ++ni)
            bb[ni] = bias[tileN + wn + ni * 16 + l15];
    }

#pragma unroll
    for (int mi = 0; mi < 4; ++mi) {
#pragma unroll
        for (int r = 0; r < 4; ++r) {
            int gm = tileM + wm + mi * 16 + quad * 4 + r;
            float rowmask = 1.f;
            if (EPI == 2) rowmask = mask[gm] ? 1.f : 0.f;
#pragma unroll
            for (int ni = 0; ni < 4; ++ni) {
                int gn = tileN + wn + ni * 16 + l15;
                float v = acc[mi][ni][r] * alpha;
                long ci = cOff + (long)gm * ldc + gn;
                float r0;
                if (EPI == 0) {
                    r0 = v;
                } else if (EPI == 1) {
                    r0 = gelu_fast(v + bb[ni]);
                } else if (EPI == 2) {
                    float h = resid[(long)gm * ldc + gn];
                    r0 = h + gscale * v * rowmask;
                } else {
                    float h = resid[(long)gm * ldc + gn];
                    r0 = h + gscale * (v + bb[ni]);
                }
                C[ci] = (TC)r0;
            }
        }
    }
}

// ---------------------------------------------------------------------------
// Deep-pipelined 256x256 GEMM for h1: C = gelu(A @ Bt^T + bias), bf16 out.
// BK=32, 3-deep LDS ring (96KB), counted vmcnt(8). Measured 620 TF (r2).
// + XCD-chunked swizzle.
// ---------------------------------------------------------------------------
__global__ __launch_bounds__(512, 2)
void gemm256_h1(const bf16* __restrict__ A, const bf16* __restrict__ Bt,
                bf16* __restrict__ C, int K, int lda, int ldb, int ldc,
                const float* __restrict__ bias)
{
    __shared__ bf16 lds[3][2][8192];   // [buf][A/B][kc*256+row][8] 16KB each

    int bx = blockIdx.x, by = blockIdx.y, bz = blockIdx.z;
    xcd_swizzle(bx, by, bz);

    int tid = threadIdx.x;
    int wave = tid >> 6, lane = tid & 63, quad = lane >> 4, l15 = lane & 15;
    int wm = (wave >> 2) * 128, wn = (wave & 3) * 64;
    int tileN = bx * 256, tileM = by * 256;

    int c0 = tid, c1 = 512 + tid;
    int kc0 = c0 >> 8, row0 = c0 & 255;
    int kc1 = c1 >> 8, row1 = c1 & 255;
    const bf16* A0 = A + (long)(tileM + row0) * lda + kc0 * 8;
    const bf16* A1 = A + (long)(tileM + row1) * lda + kc1 * 8;
    const bf16* B0 = Bt + (long)(tileN + row0) * ldb + kc0 * 8;
    const bf16* B1 = Bt + (long)(tileN + row1) * ldb + kc1 * 8;

    f32x4 acc[8][4] = {};

    int aoff = (quad * 256 + wm + l15) * 8;
    int boff = (quad * 256 + wn + l15) * 8;

    auto stage = [&](int t, int b) {
        int k0 = t * 32;
        g2l16(&lds[b][0][c0 * 8], A0 + k0);
        g2l16(&lds[b][0][c1 * 8], A1 + k0);
        g2l16(&lds[b][1][c0 * 8], B0 + k0);
        g2l16(&lds[b][1][c1 * 8], B1 + k0);
    };

    stage(0, 0);
    stage(1, 1);

    int T = K >> 5;
    int cb = 0;
    for (int t = 0; t < T; ++t) {
        int nb = cb + 2; if (nb >= 3) nb -= 3;
        stage(t + 2, nb);   // garbage for t >= T-2; never consumed (in-ws reads)

        asm volatile("s_waitcnt vmcnt(8)\n\ts_barrier" ::: "memory");

        const bf16* pA = &lds[cb][0][0];
        const bf16* pB = &lds[cb][1][0];
        bf16x8 af[8], bq[4];
#pragma unroll
        for (int mi = 0; mi < 8; ++mi)
            af[mi] = *(const bf16x8*)&pA[aoff + mi * 128];
#pragma unroll
        for (int ni = 0; ni < 4; ++ni)
            bq[ni] = *(const bf16x8*)&pB[boff + ni * 128];

        __builtin_amdgcn_s_setprio(1);
#pragma unroll
        for (int mi = 0; mi < 8; ++mi)
#pragma unroll
            for (int ni = 0; ni < 4; ++ni)
                acc[mi][ni] = __builtin_amdgcn_mfma_f32_16x16x32_bf16(
                    af[mi], bq[ni], acc[mi][ni], 0, 0, 0);
        __builtin_amdgcn_s_setprio(0);

        asm volatile("s_barrier" ::: "memory");
        cb = (cb == 2) ? 0 : cb + 1;
    }

    float bb[4];
#pragma unroll
    for (int ni = 0; ni < 4; ++ni)
        bb[ni] = bias[tileN + wn + ni * 16 + l15];

#pragma unroll
    for (int mi = 0; mi < 8; ++mi) {
#pragma unroll
        for (int r = 0; r < 4; ++r) {
            int gm = tileM + wm + mi * 16 + quad * 4 + r;
#pragma unroll
            for (int ni = 0; ni < 4; ++ni) {
                int gn = tileN + wn + ni * 16 + l15;
                float x = acc[mi][ni][r] + bb[ni];
                C[(long)gm * ldc + gn] = (bf16)gelu_fast(x);
            }
        }
    }
}

// ---------------------------------------------------------------------------
// LayerNorm over rows of 2048 (f32 in, f32 params, bf16 out). One row/block.
// ---------------------------------------------------------------------------
__global__ __launch_bounds__(256)
void ln_k(const float* __restrict__ x, const float* __restrict__ g, const float* __restrict__ b,
          bf16* __restrict__ out)
{
    long row = blockIdx.x;
    int tid = threadIdx.x;
    int wave = tid >> 6, lane = tid & 63;
    const float* px = x + row * 2048 + tid * 8;

    float4 a = *(const float4*)px;
    float4 c = *(const float4*)(px + 4);
    float f[8] = {a.x, a.y, a.z, a.w, c.x, c.y, c.z, c.w};

    float s = 0.f, s2 = 0.f;
#pragma unroll
    for (int j = 0; j < 8; ++j) { s += f[j]; s2 += f[j] * f[j]; }
    for (int o = 32; o; o >>= 1) { s += __shfl_xor(s, o, 64); s2 += __shfl_xor(s2, o, 64); }

    __shared__ float red[8];
    if (lane == 0) { red[wave] = s; red[4 + wave] = s2; }
    __syncthreads();
    s  = red[0] + red[1] + red[2] + red[3];
    s2 = red[4] + red[5] + red[6] + red[7];

    float mean = s * (1.f / 2048.f);
    float var  = s2 * (1.f / 2048.f) - mean * mean;
    float rstd = rsqrtf(var + 1e-5f);

    int col = tid * 8;
    bf16x8 o8;
#pragma unroll
    for (int j = 0; j < 8; ++j)
        o8[j] = (bf16)((f[j] - mean) * rstd * g[col + j] + b[col + j]);
    *(bf16x8*)(out + row * 2048 + tid * 8) = o8;
}

// ---------------------------------------------------------------------------
// Row softmax over 512 (in-place, bf16). One wave per row, 4 rows per block.
// ---------------------------------------------------------------------------
__global__ __launch_bounds__(256)
void softmax512(bf16* __restrict__ s)
{
    long row = (long)blockIdx.x * 4 + (threadIdx.x >> 6);
    int lane = threadIdx.x & 63;
    bf16* p = s + row * 512 + lane * 8;
    bf16x8 v = *(const bf16x8*)p;
    float f[8], mx = -1e30f;
#pragma unroll
    for (int j = 0; j < 8; ++j) { f[j] = (float)v[j]; mx = fmaxf(mx, f[j]); }
    for (int o = 32; o; o >>= 1) mx = fmaxf(mx, __shfl_xor(mx, o, 64));
    float sum = 0.f;
#pragma unroll
    for (int j = 0; j < 8; ++j) { f[j] = __expf(f[j] - mx); sum += f[j]; }
    for (int o = 32; o; o >>= 1) sum += __shfl_xor(sum, o, 64);
    float r = 1.f / sum;
    bf16x8 o8;
#pragma unroll
    for (int j = 0; j < 8; ++j) o8[j] = (bf16)(f[j] * r);
    *(bf16x8*)p = o8;
}

// ---------------------------------------------------------------------------
// Transpose f32 -> bf16: out[n][m] = (bf16)in[m][n]. Tile 32x32, block 256.
// ---------------------------------------------------------------------------
__global__ __launch_bounds__(256)
void transpose_cvt(const float* __restrict__ in, bf16* __restrict__ out, int ldi, int ldo)
{
    __shared__ float t[32][33];
    int tx = threadIdx.x & 31, ty = threadIdx.x >> 5;
    int n0 = blockIdx.x * 32, m0 = blockIdx.y * 32;
#pragma unroll
    for (int i = 0; i < 4; ++i)
        t[ty + i * 8][tx] = in[(long)(m0 + ty + i * 8) * ldi + n0 + tx];
    __syncthreads();
#pragma unroll
    for (int i = 0; i < 4; ++i)
        out[(long)(n0 + ty + i * 8) * ldo + m0 + tx] = (bf16)t[tx][ty + i * 8];
}

// ---------------------------------------------------------------------------
// Batched bf16 transpose (for V): out[n][m] = in[m][n]. Tile 32x32.
// ---------------------------------------------------------------------------
__global__ __launch_bounds__(256)
void transpose_k(const bf16* __restrict__ in, bf16* __restrict__ out,
                 int ldi, int ldo, long sIo, long sIi, long sOo, long sOi, int zInner)
{
    int z = blockIdx.z;
    in  += (long)(z / zInner) * sIo + (long)(z % zInner) * sIi;
    out += (long)(z / zInner) * sOo + (long)(z % zInner) * sOi;
    __shared__ bf16 t[32][33];
    int tx = threadIdx.x & 31, ty = threadIdx.x >> 5;
    int n0 = blockIdx.x * 32, m0 = blockIdx.y * 32;
#pragma unroll
    for (int i = 0; i < 4; ++i)
        t[ty + i * 8][tx] = in[(long)(m0 + ty + i * 8) * ldi + n0 + tx];
    __syncthreads();
#pragma unroll
    for (int i = 0; i < 4; ++i)
        out[(long)(n0 + ty + i * 8) * ldo + m0 + tx] = t[tx][ty + i * 8];
}

// f32 -> bf16 elementwise (for image_embeds). 4 elems/thread.
__global__ __launch_bounds__(256)
void cvt_k(const float* __restrict__ in, bf16* __restrict__ out)
{
    int i = (blockIdx.x * 256 + threadIdx.x) * 4;
    float4 v = *(const float4*)(in + i);
    out[i + 0] = (bf16)v.x;
    out[i + 1] = (bf16)v.y;
    out[i + 2] = (bf16)v.z;
    out[i + 3] = (bf16)v.w;
}

// ---------------------------------------------------------------------------
// Workspace layout (MiB offsets), peak 176 MiB:
//   0-32   : WqT(0) WkT(8) WvT(16) WoT(24)  -> later W1T(0-32)
//   32-48  : xln        -> later W2T low half
//   48-64  : q/attn_out -> later W2T high half
//   64-68  : kbuf   68-72: vbuf   72-76: vt   76-80: imgb
//   80-144 : sc (scores -> P -> h1)
//   144-176: x2 (f32)
// Tail garbage reads (<=256B past each GEMM operand) all land inside ws.
// ---------------------------------------------------------------------------
extern "C" void kernel_launch(void* const* d_in, const int* in_sizes, int n_in,
                              void* d_out, int out_size, void* d_ws, size_t ws_size,
                              hipStream_t stream)
{
    const float* hidden = (const float*)d_in[0];  // (2,2048,2048) f32
    const float* image  = (const float*)d_in[1];  // (2,8,64,2048) f32
    const int*   media  = (const int*)d_in[2];    // (2,2048)
    const float* Wq = (const float*)d_in[3];
    const float* Wk = (const float*)d_in[4];
    const float* Wv = (const float*)d_in[5];
    const float* Wo = (const float*)d_in[6];
    const float* lag = (const float*)d_in[7];
    const float* lab = (const float*)d_in[8];
    const float* lfg = (const float*)d_in[9];
    const float* lfb = (const float*)d_in[10];
    const float* W1 = (const float*)d_in[11];     // (2048, 8192)
    const float* b1 = (const float*)d_in[12];
    const float* W2 = (const float*)d_in[13];     // (8192, 2048)
    const float* b2 = (const float*)d_in[14];
    const float* ga = (const float*)d_in[15];
    const float* gf = (const float*)d_in[16];
    float* out = (float*)d_out;

    char* ws = (char*)d_ws;
    const size_t MB = 1ull << 20;
    bf16* WqT  = (bf16*)(ws + 0);
    bf16* WkT  = (bf16*)(ws + 8 * MB);
    bf16* WvT  = (bf16*)(ws + 16 * MB);
    bf16* WoT  = (bf16*)(ws + 24 * MB);
    bf16* W1T  = (bf16*)(ws + 0);         // reuses Wq..Wo region after attn
    bf16* W2T  = (bf16*)(ws + 32 * MB);   // reuses xln+q region after h1
    bf16* xln  = (bf16*)(ws + 32 * MB);
    bf16* q    = (bf16*)(ws + 48 * MB);
    bf16* kbuf = (bf16*)(ws + 64 * MB);
    bf16* vbuf = (bf16*)(ws + 68 * MB);
    bf16* vt   = (bf16*)(ws + 72 * MB);
    bf16* imgb = (bf16*)(ws + 76 * MB);
    bf16* sc   = (bf16*)(ws + 80 * MB);
    float* x2  = (float*)(ws + 144 * MB);

    const float SCALE = 0.08838834764831845f; // 128^-0.5
    dim3 blk(256);

    // f32 -> bf16 conversions / transposes
    transpose_cvt<<<dim3(64, 64, 1), blk, 0, stream>>>(Wq, WqT, 2048, 2048);
    transpose_cvt<<<dim3(64, 64, 1), blk, 0, stream>>>(Wk, WkT, 2048, 2048);
    transpose_cvt<<<dim3(64, 64, 1), blk, 0, stream>>>(Wv, WvT, 2048, 2048);
    transpose_cvt<<<dim3(64, 64, 1), blk, 0, stream>>>(Wo, WoT, 2048, 2048);
    cvt_k<<<2048, blk, 0, stream>>>(image, imgb);   // 2*512*2048 elems

    // x = LN(hidden)  (f32 in, bf16 out)
    ln_k<<<4096, blk, 0, stream>>>(hidden, lag, lab, xln);

    // q = x @ Wq   (M=4096, N=2048, K=2048)
    gemm_bt<0, bf16><<<dim3(16, 32, 1), blk, 0, stream>>>(
        xln, WqT, q, 2048, 2048, 2048, 2048, 0, 0, 0, 0, 0, 0, 1, 1.f,
        nullptr, nullptr, nullptr, nullptr);

    // k, v = image @ {Wk, Wv}  (M=1024, N=2048, K=2048; zi=0 -> k, zi=1 -> v)
    gemm_bt<0, bf16><<<dim3(16, 8, 2), blk, 0, stream>>>(
        imgb, WkT, kbuf, 2048, 2048, 2048, 2048,
        0, 0, 0, 4194304, 0, 2097152, 2, 1.f,
        nullptr, nullptr, nullptr, nullptr);

    // vt[b][h][d][kv] = v[b][kv][h*128+d]
    transpose_k<<<dim3(4, 16, 32), blk, 0, stream>>>(
        vbuf, vt, 2048, 512, 1048576, 128, 1048576, 65536, 16);

    // scores[b][h][s][kv] = SCALE * q_bh @ k_bh^T  (M=2048, N=512, K=128)
    gemm_bt<0, bf16><<<dim3(4, 16, 32), blk, 0, stream>>>(
        q, kbuf, sc, 128, 2048, 2048, 512,
        4194304, 128, 1048576, 128, 16777216, 1048576, 16, SCALE,
        nullptr, nullptr, nullptr, nullptr);

    // softmax over kv (in place)
    softmax512<<<16384, blk, 0, stream>>>(sc);

    // attn_out[b][s][h*128+d] = P_bh @ vt_bh^T  (M=2048, N=128, K=512)
    gemm_bt<0, bf16><<<dim3(1, 16, 32), blk, 0, stream>>>(
        sc, vt, q, 512, 512, 512, 2048,
        16777216, 1048576, 1048576, 65536, 4194304, 128, 16, 1.f,
        nullptr, nullptr, nullptr, nullptr);

    // x2 = hidden + tanh(ga) * (attn_out @ Wo) * mask   (f32 out)
    gemm_bt<2, float><<<dim3(16, 32, 1), blk, 0, stream>>>(
        q, WoT, x2, 2048, 2048, 2048, 2048, 0, 0, 0, 0, 0, 0, 1, 1.f,
        hidden, nullptr, ga, media);

    // FFN weights (reuse dead regions)
    transpose_cvt<<<dim3(256, 64, 1), blk, 0, stream>>>(W1, W1T, 8192, 2048);

    // ln2 = LN(x2)
    ln_k<<<4096, blk, 0, stream>>>(x2, lfg, lfb, xln);

    // h1 = gelu(ln2 @ W1 + b1)  (M=4096, N=8192, K=2048) — 256^2 3-ring (620 TF)
    gemm256_h1<<<dim3(32, 16, 1), dim3(512), 0, stream>>>(
        xln, W1T, sc, 2048, 2048, 2048, 8192, b1);

    // W2T after h1 (xln, q dead now)
    transpose_cvt<<<dim3(64, 256, 1), blk, 0, stream>>>(W2, W2T, 2048, 8192);

    // out = x2 + tanh(gf) * (h1 @ W2 + b2)  (M=4096, N=2048, K=8192, f32 out)
    gemm_bt<3, float><<<dim3(16, 32, 1), blk, 0, stream>>>(
        sc, W2T, out, 8192, 8192, 8192, 2048, 0, 0, 0, 0, 0, 0, 1, 1.f,
        x2, b2, gf, nullptr);
}